// Round 10
// baseline (82.141 us; speedup 1.0000x reference)
//
#include <hip/hip_runtime.h>

namespace {

constexpr int F     = 128;
constexpr int L     = 4096;
constexpr int NTASK = 4096;   // 131072 rows / 32 rows per task
constexpr int TPB   = 8;      // tasks per block (contiguous span)
constexpr int NB    = NTASK / TPB;   // 512 blocks = 2/CU

using short8 = __attribute__((ext_vector_type(8))) short;
using f32x16 = __attribute__((ext_vector_type(16))) float;
using u32x4  = __attribute__((ext_vector_type(4))) unsigned int;

__device__ inline unsigned short f2bf(float x) {
    unsigned u = __builtin_bit_cast(unsigned, x);
    unsigned r = (u + 0x7fffu + ((u >> 16) & 1u)) >> 16;
    return (unsigned short)r;
}

__device__ inline unsigned pack2(float lo, float hi) {
    return (unsigned)f2bf(lo) | ((unsigned)f2bf(hi) << 16);
}

__device__ inline short8 cvt8(float4 a, float4 b) {
    u32x4 u;
    u[0] = pack2(a.x, a.y);
    u[1] = pack2(a.z, a.w);
    u[2] = pack2(b.x, b.y);
    u[3] = pack2(b.z, b.w);
    return __builtin_bit_cast(short8, u);
}

// Head-folded weights packed as 32x32x16 MFMA first-operand fragments.
//   chunk c = cg*16 + S (cg: col-group 0..3, S: k-step 0..15), lane l, j 0..7
//   Wf[(c*64 + l)*8 + j] = Wbar[k][n]
//   h = l>>5, n = cg*32 + (l&31)
//   k = S*16 + (j>>2)*8 + h*4 + (j&3)      <-- matches dense 32B/row loads
//   Wbar[k][n]: k<128 -> mean_h W_src[(h*128+n)*128+k]
//              k>=128 -> mean_h W_res[(h*128+n)*128+(k-128)]
__global__ void prep(const float* __restrict__ Wsrc,
                     const float* __restrict__ Wres,
                     const float* __restrict__ bias,
                     unsigned short* __restrict__ Wf,
                     float* __restrict__ bbar)
{
    int idx = blockIdx.x * 256 + threadIdx.x;
    if (idx < 2 * F * F) {
        int j  = idx & 7;
        int r  = idx >> 3;
        int l  = r & 63;
        int c  = r >> 6;          // 0..63
        int cg = c >> 4;
        int S  = c & 15;
        int h  = l >> 5;
        int k  = S * 16 + ((j >> 2) << 3) + (h << 2) + (j & 3);
        int n  = (cg << 5) + (l & 31);
        int e  = k & (F - 1);
        const float* W = (k < F) ? Wsrc : Wres;
        float sum = 0.f;
#pragma unroll
        for (int hh = 0; hh < 8; ++hh) sum += W[(hh * F + n) * F + e];
        Wf[idx] = f2bf(sum * 0.125f);
    }
    if (idx < F) {
        float s = 0.f;
#pragma unroll
        for (int hh = 0; hh < 8; ++hh) s += bias[hh * F + idx];
        bbar[idx] = s * 0.125f;
    }
}

// No LDS, no barriers. Wave = 32 rows x 32 cols per task; W slice pinned in
// 64 VGPRs; per task: 32 back-to-back dwordx4 loads (deep MLP), 16 MFMAs
// consuming in issue order, 4 float4 stores.
__global__ __launch_bounds__(256, 2)
void gat32(const float* __restrict__ loc,
           const unsigned short* __restrict__ Wf,
           const float* __restrict__ bbar,
           float* __restrict__ out)
{
    const int t    = threadIdx.x;
    const int lane = t & 63;
    const int cg   = t >> 6;       // col-group 0..3
    const int l31  = lane & 31;
    const int h    = lane >> 5;

    // persistent W fragments (16 x 4 VGPR = 64), asm-pinned against remat
    u32x4 wu[16];
#pragma unroll
    for (int s = 0; s < 16; ++s)
        wu[s] = *(const u32x4*)(Wf + (((cg * 16 + s) * 64 + lane) << 3));
#pragma unroll
    for (int s = 0; s < 16; ++s) {
        unsigned a = wu[s][0], b = wu[s][1], c = wu[s][2], d = wu[s][3];
        asm volatile("" : "+v"(a), "+v"(b), "+v"(c), "+v"(d));
        wu[s][0] = a; wu[s][1] = b; wu[s][2] = c; wu[s][3] = d;
    }

    const int cbase = cg * 32 + h * 4;
    float4 bb[4];
#pragma unroll
    for (int q = 0; q < 4; ++q) bb[q] = *(const float4*)(bbar + cbase + q * 8);

    const int task0 = blockIdx.x * TPB;
#pragma unroll 1
    for (int it = 0; it < TPB; ++it) {
        const int task = task0 + it;
        const int row  = task * 32 + l31;
        const int p    = row & (L - 1);
        const float* cp = loc + (size_t)row * F;
        const float* pp = (p == 0) ? cp : cp - F;

        // ---- 32 back-to-back loads: prev row then cur row.
        // instr i reads 16B at byte offset i*32 + h*16 -> per-instruction the
        // wave covers 32 rows x 32B CONTIGUOUS.
        float4 Abuf[32];
#pragma unroll
        for (int i = 0; i < 16; ++i)
            Abuf[i] = *(const float4*)(pp + i * 8 + h * 4);
#pragma unroll
        for (int i = 0; i < 16; ++i)
            Abuf[16 + i] = *(const float4*)(cp + i * 8 + h * 4);

        f32x16 acc;
#pragma unroll
        for (int i = 0; i < 16; ++i) acc[i] = 0.f;

        // consume in issue order: MFMA s uses Abuf[2s], Abuf[2s+1]
#pragma unroll
        for (int s = 0; s < 16; ++s) {
            acc = __builtin_amdgcn_mfma_f32_32x32x16_bf16(
                __builtin_bit_cast(short8, wu[s]),
                cvt8(Abuf[2 * s], Abuf[2 * s + 1]), acc, 0, 0, 0);
        }

        // ---- stores: lane owns row `row`; reg r -> out-col cbase + (r&3) + 8*(r>>2)
        float* orow = out + (size_t)row * F;
        const bool isfirst = (p == 0);
#pragma unroll
        for (int q = 0; q < 4; ++q) {
            int c0 = cbase + q * 8;
            float4 v = make_float4(acc[q * 4 + 0] + bb[q].x, acc[q * 4 + 1] + bb[q].y,
                                   acc[q * 4 + 2] + bb[q].z, acc[q * 4 + 3] + bb[q].w);
            if (isfirst) v = *(const float4*)(cp + c0);   // out[b,0,:] = loc[b,0,:]
            *(float4*)(orow + c0) = v;
        }
    }
}

} // namespace

extern "C" void kernel_launch(void* const* d_in, const int* in_sizes, int n_in,
                              void* d_out, int out_size, void* d_ws, size_t ws_size,
                              hipStream_t stream) {
    const float* loc  = (const float*)d_in[0];
    const float* Wsrc = (const float*)d_in[1];
    // d_in[2] W_dst, d_in[3] attn_l, d_in[4] attn_r cancel (alpha == 1)
    const float* Wres = (const float*)d_in[5];
    const float* bias = (const float*)d_in[6];

    unsigned short* Wf   = (unsigned short*)d_ws;          // 32768 bf16 = 64 KB
    float*          bbar = (float*)((char*)d_ws + 2 * F * F * 2);
    float*          outp = (float*)d_out;

    prep<<<128, 256, 0, stream>>>(Wsrc, Wres, bias, Wf, bbar);

    gat32<<<NB, 256, 0, stream>>>(loc, Wf, bbar, outp);
}

// Round 11
// 31.897 us; speedup vs baseline: 2.5752x; 2.5752x over previous
//
#include <hip/hip_runtime.h>

namespace {

constexpr int F = 128;
constexpr int L = 4096;

using short8 = __attribute__((ext_vector_type(8))) short;
using f32x16 = __attribute__((ext_vector_type(16))) float;
using u32x4  = __attribute__((ext_vector_type(4))) unsigned int;

__device__ inline unsigned short f2bf(float x) {
    unsigned u = __builtin_bit_cast(unsigned, x);
    unsigned r = (u + 0x7fffu + ((u >> 16) & 1u)) >> 16;
    return (unsigned short)r;
}

__device__ inline unsigned pack2(float lo, float hi) {
    return (unsigned)f2bf(lo) | ((unsigned)f2bf(hi) << 16);
}

// Head-folded weights packed as 32x32x16 MFMA SECOND-operand fragments:
//   Wf[((cg*16 + S)*64 + l)*8 + j] = Wbar[k][n]
//   h = l>>5, n = cg*32 + (l&31), k = S*16 + h*8 + j
//   Wbar[k][n]: k<128 -> mean_h W_src[(h*128+n)*128+k]
//              k>=128 -> mean_h W_res[(h*128+n)*128+(k-128)]
__global__ void prep(const float* __restrict__ Wsrc,
                     const float* __restrict__ Wres,
                     const float* __restrict__ bias,
                     unsigned short* __restrict__ Wf,
                     float* __restrict__ bbar)
{
    int idx = blockIdx.x * 256 + threadIdx.x;
    if (idx < 2 * F * F) {
        int j  = idx & 7;
        int r2 = idx >> 3;
        int l  = r2 & 63;
        int c  = r2 >> 6;          // 0..63
        int cg = c >> 4;
        int S  = c & 15;
        int h  = l >> 5;
        int k  = S * 16 + h * 8 + j;
        int n  = (cg << 5) + (l & 31);
        int e  = k & (F - 1);
        const float* W = (k < F) ? Wsrc : Wres;
        float sum = 0.f;
#pragma unroll
        for (int hh = 0; hh < 8; ++hh) sum += W[(hh * F + n) * F + e];
        Wf[idx] = f2bf(sum * 0.125f);
    }
    if (idx < F) {
        float s = 0.f;
#pragma unroll
        for (int hh = 0; hh < 8; ++hh) s += bias[hh * F + idx];
        bbar[idx] = s * 0.125f;
    }
}

// Block = 64 output rows x 128 cols, 4 waves (wave = 32-col group, 64 rows).
// All global accesses wave-contiguous; A through swizzled LDS; W in VGPRs.
__global__ __launch_bounds__(256, 2)
void gat_cg(const float* __restrict__ loc,
            const unsigned short* __restrict__ Wf,
            const float* __restrict__ bbar,
            float* __restrict__ out)
{
    __shared__ unsigned short As[65 * 128];   // 65 rows x 256B, XOR-swizzled

    const int t    = threadIdx.x;
    const int lane = t & 63;
    const int cg   = t >> 6;       // col-group 0..3
    const int l31  = lane & 31;
    const int h    = lane >> 5;
    const long rowbase = (long)blockIdx.x * 64;

    // ---- W slice: 16 x b128 lane-linear (64 VGPR, lives whole kernel)
    u32x4 wu[16];
#pragma unroll
    for (int s = 0; s < 16; ++s)
        wu[s] = *(const u32x4*)(Wf + (((cg * 16 + s) * 64 + lane) << 3));

    const float bb = bbar[cg * 32 + l31];

    // ---- stage A: global rows rowbase-1 .. rowbase+63 -> LDS rows 0..64
    // contiguous 32B/lane reads; bf16 + (row&15)<<4 XOR swizzle on write
#pragma unroll
    for (int i = 0; i < 5; ++i) {
        int c = i * 256 + t;
        if (i < 4 || c < 1040) {               // 65 rows * 16 chunks
            int r  = c >> 4;
            int sl = c & 15;
            long g = rowbase - 1 + r;
            if (g < 0) g = 0;                  // tb==0 halo clamp (value unused)
            const float* src = loc + g * F + sl * 8;
            float4 v0 = *(const float4*)(src);
            float4 v1 = *(const float4*)(src + 4);
            u32x4 pk;
            pk[0] = pack2(v0.x, v0.y);
            pk[1] = pack2(v0.z, v0.w);
            pk[2] = pack2(v1.x, v1.y);
            pk[3] = pack2(v1.z, v1.w);
            *(u32x4*)((char*)As + r * 256 + ((sl * 16) ^ ((r & 15) << 4))) = pk;
        }
    }
    __syncthreads();

    // ---- compute: 2 row-tiles x 16 k-steps; s<8 uses prev rows (LDS r+0),
    // s>=8 uses cur rows (LDS r+1)
    f32x16 acc0, acc1;
#pragma unroll
    for (int i = 0; i < 16; ++i) { acc0[i] = 0.f; acc1[i] = 0.f; }

#pragma unroll
    for (int s = 0; s < 16; ++s) {
        const int d   = (s < 8) ? 0 : 1;
        const int off = (s & 7) * 32 + h * 16;
        const int r0  = l31 + d;
        const int r1  = 32 + l31 + d;
        short8 x0 = *(const short8*)((const char*)As + r0 * 256 + (off ^ ((r0 & 15) << 4)));
        short8 x1 = *(const short8*)((const char*)As + r1 * 256 + (off ^ ((r1 & 15) << 4)));
        short8 w  = __builtin_bit_cast(short8, wu[s]);
        acc0 = __builtin_amdgcn_mfma_f32_32x32x16_bf16(x0, w, acc0, 0, 0, 0);
        acc1 = __builtin_amdgcn_mfma_f32_32x32x16_bf16(x1, w, acc1, 0, 0, 0);
    }

    // ---- stores: D col = lane&31 -> out-col; each dword store covers
    // 2 rows x 128B contiguous lines
    const int col = cg * 32 + l31;
#pragma unroll
    for (int reg = 0; reg < 16; ++reg) {
        const int rl = (reg & 3) + 8 * (reg >> 2) + 4 * h;
        {
            long grow = rowbase + rl;
            float v = acc0[reg] + bb;
            if ((grow & (L - 1)) == 0) v = loc[grow * F + col];  // out[b,0,:] = loc[b,0,:]
            out[grow * F + col] = v;
        }
        {
            long grow = rowbase + 32 + rl;   // rows 32..63: never p==0
            out[grow * F + col] = acc1[reg] + bb;
        }
    }
}

} // namespace

extern "C" void kernel_launch(void* const* d_in, const int* in_sizes, int n_in,
                              void* d_out, int out_size, void* d_ws, size_t ws_size,
                              hipStream_t stream) {
    const float* loc  = (const float*)d_in[0];
    const float* Wsrc = (const float*)d_in[1];
    // d_in[2] W_dst, d_in[3] attn_l, d_in[4] attn_r cancel (alpha == 1)
    const float* Wres = (const float*)d_in[5];
    const float* bias = (const float*)d_in[6];

    unsigned short* Wf   = (unsigned short*)d_ws;          // 32768 bf16 = 64 KB
    float*          bbar = (float*)((char*)d_ws + 2 * F * F * 2);
    float*          outp = (float*)d_out;

    prep<<<128, 256, 0, stream>>>(Wsrc, Wres, bias, Wf, bbar);

    // 131072 rows / 64 rows per block = 2048 blocks
    gat_cg<<<2048, 256, 0, stream>>>(loc, Wf, bbar, outp);
}